// Round 1
// 205.017 us; speedup vs baseline: 1.0888x; 1.0888x over previous
//
#include <hip/hip_runtime.h>
#include <hip/hip_bf16.h>

// 3x3 conv pad=1 stride=1, NHWC fp32 -> bf16 MFMA implicit GEMM.
//   M = 32*56*56 = 100352, N = 256, K = 9*128 = 1152
// R5: 256x256 tile, BK=64, 8 waves (2Mx4N), 128 KiB LDS, 8-phase-per-2-K-tiles
// schedule with COUNTED vmcnt(8) (never 0 in steady state) + s_setprio around
// MFMA clusters (T3+T4+T5).  R4's 2-phase structure capped at ~540 TF
// (MfmaUtil 22%) -- the vmcnt(0)+barrier drain per K-step is structural.
// Here staging runs 6 phases ahead of consumption at K-half granularity:
//   phase p of K-tile t stages: p0 -> A-k1(t+1), p1 -> B-k1(t+1),
//                               p2 -> A-k0(t+2), p3 -> B-k0(t+2)
// and each region overwrite is issued only after the barrier following the
// last reads of that region (provable: khalf0 regions are last read at phase
// 1, khalf1 at phase 3).  vmcnt(8) at end of phases 1/3 leaves exactly the 4
// newest half-stages (8 loads) in flight while guaranteeing the next phase's
// data.  LDS swizzle: 16B-chunk kc ^= (row>>1)&3 within 64 B rows -> each
// ds_read_b128 hits every bank exactly 8x (uniform = conflict-free); the
// global source is pre-swizzled so the linear global_load_lds DMA lands data
// at swizzled positions (both-sides rule).

#define NIMG 32
#define HH 56
#define WW 56
#define PH 58
#define PW 58
#define CIN 128
#define COUT 256
#define KTOT 1152
#define PAD_ELEMS (NIMG * PH * PW * CIN)

#define BK 64
#define NT (KTOT / BK)        // 18 K-tiles
#define NBLK ((NIMG * HH * WW) / 256)   // 392 = 8 * 49

typedef __attribute__((ext_vector_type(8))) short bf16x8;
typedef __attribute__((ext_vector_type(4))) short s16x4;
typedef __attribute__((ext_vector_type(4))) float f32x4;

__device__ __forceinline__ short f2bf(float x) {
    union { __hip_bfloat16 b; short s; } u;
    u.b = __float2bfloat16(x);
    return u.s;
}

typedef const void __attribute__((address_space(1)))* gas1_t;
typedef void __attribute__((address_space(3)))* las3_t;
__device__ __forceinline__ void async16(short* lds_p, const short* g) {
    __builtin_amdgcn_global_load_lds((gas1_t)g, (las3_t)lds_p, 16, 0, 0);
}

// ---- pack 1: fp32 NHWC -> padded bf16 (32,58,58,128), zero halo -------------
__global__ __launch_bounds__(256) void pack_input(const float* __restrict__ in,
                                                  short* __restrict__ pad) {
    const int tid  = blockIdx.x * 256 + threadIdx.x;
    const int flat = tid * 8;
    const int c8   = flat & (CIN - 1);
    const int rest = flat >> 7;
    const int iw   = rest % PW;
    const int r2   = rest / PW;
    const int ih   = r2 % PH;
    const int img  = r2 / PH;
    bf16x8 v = (bf16x8)0;
    if (ih >= 1 && ih <= HH && iw >= 1 && iw <= WW) {
        const float* p = in + (((size_t)(img * HH + ih - 1) * WW + (iw - 1)) * CIN + c8);
        const float4 x0 = *(const float4*)p;
        const float4 x1 = *(const float4*)(p + 4);
        v.s0 = f2bf(x0.x); v.s1 = f2bf(x0.y); v.s2 = f2bf(x0.z); v.s3 = f2bf(x0.w);
        v.s4 = f2bf(x1.x); v.s5 = f2bf(x1.y); v.s6 = f2bf(x1.z); v.s7 = f2bf(x1.w);
    }
    *(bf16x8*)(pad + flat) = v;
}

// ---- pack 2: weights (K=1152, N=256) fp32 -> bf16 transposed [n][k] ---------
__global__ __launch_bounds__(256) void pack_wgt(const float* __restrict__ w,
                                                short* __restrict__ wt) {
    __shared__ short tile[32][33];
    const int k0 = blockIdx.x * 32;
    const int n0 = blockIdx.y * 32;
    const int t  = threadIdx.x;
    {
        const int kl  = t >> 3;
        const int nl4 = (t & 7) * 4;
        const float4 x = *(const float4*)(w + (size_t)(k0 + kl) * COUT + n0 + nl4);
        tile[kl][nl4 + 0] = f2bf(x.x);
        tile[kl][nl4 + 1] = f2bf(x.y);
        tile[kl][nl4 + 2] = f2bf(x.z);
        tile[kl][nl4 + 3] = f2bf(x.w);
    }
    __syncthreads();
    {
        const int nl  = t >> 3;
        const int kl4 = (t & 7) * 4;
        s16x4 v;
        v.x = tile[kl4 + 0][nl];
        v.y = tile[kl4 + 1][nl];
        v.z = tile[kl4 + 2][nl];
        v.w = tile[kl4 + 3][nl];
        *(s16x4*)(wt + (size_t)(n0 + nl) * KTOT + k0 + kl4) = v;
    }
}

// ---- GEMM: 256x256 tile, BK=64, 8-phase schedule, 16x16x32 bf16 MFMA --------
#define FENCE() asm volatile("" ::: "memory")
#define BARRIER() do { FENCE(); __builtin_amdgcn_s_barrier(); FENCE(); } while (0)
#define VMWAIT(N) asm volatile("s_waitcnt vmcnt(" #N ")" ::: "memory")
#define NOSTMT ((void)0)

__global__ __launch_bounds__(512, 2) void conv_mfma(const short* __restrict__ apad,
                                                    const short* __restrict__ bwt,
                                                    const float* __restrict__ bias,
                                                    float* __restrict__ out) {
    // LDS: 4 regions per operand of [256 rows][32 k] bf16 (16 KB each),
    // region index = buf*2 + khalf.  A at [0,32768) shorts, B at [32768,65536).
    __shared__ short lds[65536];   // 128 KiB

    const int t  = threadIdx.x;    // 0..511
    const int l  = t & 63;
    const int w  = t >> 6;         // 0..7
    const int wm = w >> 2;         // 0..1  (M half of tile)
    const int wn = w & 3;          // 0..3  (N quarter of tile)
    const int fr = l & 15;
    const int fq = l >> 4;

    // fragment lane offset (shorts) inside a region, swizzle folded in:
    // row = 16*i + fr  ->  (row>>1)&3 == (fr>>1)&3  (base is a multiple of 16)
    const int laneoff = fr * 32 + ((fq ^ ((fr >> 1) & 3))) * 8;
    // staging: thread t handles 16B chunk c = t (+512), row = c>>2, phys
    // chunk pc = t&3; logical kchunk = pc ^ ((row>>1)&3) = pc ^ ((t>>3)&3)
    const int kcs   = (t & 3) ^ ((t >> 3) & 3);
    const int wbase = w * 512;     // wave-uniform LDS base (lane*16B is HW-added)

    const int bid = blockIdx.x;
    const int swz = (bid & 7) * (NBLK / 8) + (bid >> 3);   // 392 = 8*49, bijective
    const int m0  = swz * 256;

    // global row bases for staging (rows r0 and r0+128 of the M/N tile)
    const int r0 = t >> 2;         // 0..127
    int abase0, abase1;
    {
        int m = m0 + r0;
        int img = m / (HH * WW), rem = m - img * (HH * WW);
        int oh = rem / WW, ow = rem - oh * WW;
        abase0 = ((img * PH + oh) * PW + ow) * CIN;
        m = m0 + r0 + 128;
        img = m / (HH * WW); rem = m - img * (HH * WW);
        oh = rem / WW; ow = rem - oh * WW;
        abase1 = ((img * PH + oh) * PW + ow) * CIN;
    }
    const int bbase0 = r0 * KTOT;
    const int bbase1 = (r0 + 128) * KTOT;

    f32x4 acc[8][4];
#pragma unroll
    for (int i = 0; i < 8; ++i)
#pragma unroll
        for (int j = 0; j < 4; ++j) { f32x4 z = {0.f, 0.f, 0.f, 0.f}; acc[i][j] = z; }

    bf16x8 af[8];

    // K-tile KT covers tap = KT>>1 (CIN=128, BK=64), channel base (KT&1)*64.
#define STAGE_A(KT, KH) do {                                                  \
        const int _tap = (KT) >> 1;                                           \
        const int _fh  = (_tap * 11) >> 5;   /* /3 for 0..8 */                \
        const int _fw  = _tap - 3 * _fh;                                      \
        const int _off = (_fh * PW + _fw) * CIN + ((KT) & 1) * 64             \
                         + (KH) * 32 + kcs * 8;                               \
        short* _l = lds + (((KT) & 1) * 2 + (KH)) * 8192 + wbase;             \
        async16(_l,        apad + abase0 + _off);                             \
        async16(_l + 4096, apad + abase1 + _off);                             \
    } while (0)

#define STAGE_B(KT, KH) do {                                                  \
        const int _off = (KT) * 64 + (KH) * 32 + kcs * 8;                     \
        short* _l = lds + 32768 + (((KT) & 1) * 2 + (KH)) * 8192 + wbase;     \
        async16(_l,        bwt + bbase0 + _off);                              \
        async16(_l + 4096, bwt + bbase1 + _off);                              \
    } while (0)

    // One phase: ds-read fragments || issue one half-stage || barrier ||
    // 16 MFMA under setprio || counted vmcnt || barrier.
#define PHASE(BUF, KH, NH, STAGE_STMT, WAIT_STMT) do {                        \
        const short* _a = lds + ((BUF) * 2 + (KH)) * 8192;                    \
        const short* _b = lds + 32768 + ((BUF) * 2 + (KH)) * 8192;            \
        bf16x8 _bf0, _bf1;                                                    \
        if ((NH) == 0) {                                                      \
            _Pragma("unroll")                                                 \
            for (int _i = 0; _i < 8; ++_i)                                    \
                af[_i] = *(const bf16x8*)(_a + wm * 4096 + _i * 512 + laneoff); \
        }                                                                     \
        _bf0 = *(const bf16x8*)(_b + wn * 2048 + (NH) * 1024 +   0 + laneoff); \
        _bf1 = *(const bf16x8*)(_b + wn * 2048 + (NH) * 1024 + 512 + laneoff); \
        STAGE_STMT;                                                           \
        BARRIER();                                                            \
        __builtin_amdgcn_s_setprio(1);                                        \
        _Pragma("unroll")                                                     \
        for (int _i = 0; _i < 8; ++_i) {                                      \
            acc[_i][(NH)*2+0] = __builtin_amdgcn_mfma_f32_16x16x32_bf16(      \
                af[_i], _bf0, acc[_i][(NH)*2+0], 0, 0, 0);                    \
            acc[_i][(NH)*2+1] = __builtin_amdgcn_mfma_f32_16x16x32_bf16(      \
                af[_i], _bf1, acc[_i][(NH)*2+1], 0, 0, 0);                    \
        }                                                                     \
        __builtin_amdgcn_s_setprio(0);                                        \
        WAIT_STMT;                                                            \
        BARRIER();                                                            \
    } while (0)

    // prologue: tile 0 fully + tile 1 khalf0 (6 half-stages, 12 loads);
    // vmcnt(8) guarantees tile 0's khalf0 (A,B) -- the first phase's reads.
    STAGE_A(0, 0); STAGE_B(0, 0);
    STAGE_A(0, 1); STAGE_B(0, 1);
    STAGE_A(1, 0); STAGE_B(1, 0);
    VMWAIT(8);
    BARRIER();

#pragma unroll 1
    for (int kt = 0; kt < NT - 2; kt += 2) {
        // K-tile kt (buf0)
        PHASE(0, 0, 0, STAGE_A(kt + 1, 1), NOSTMT);
        PHASE(0, 0, 1, STAGE_B(kt + 1, 1), VMWAIT(8));
        PHASE(0, 1, 0, STAGE_A(kt + 2, 0), NOSTMT);
        PHASE(0, 1, 1, STAGE_B(kt + 2, 0), VMWAIT(8));
        // K-tile kt+1 (buf1)
        PHASE(1, 0, 0, STAGE_A(kt + 2, 1), NOSTMT);
        PHASE(1, 0, 1, STAGE_B(kt + 2, 1), VMWAIT(8));
        PHASE(1, 1, 0, STAGE_A(kt + 3, 0), NOSTMT);
        PHASE(1, 1, 1, STAGE_B(kt + 3, 0), VMWAIT(8));
    }
    // tail: K-tile 16 (buf0) -- last real stages, drain waits
    PHASE(0, 0, 0, STAGE_A(NT - 1, 1), NOSTMT);
    PHASE(0, 0, 1, STAGE_B(NT - 1, 1), VMWAIT(8));
    PHASE(0, 1, 0, NOSTMT,             NOSTMT);
    PHASE(0, 1, 1, NOSTMT,             VMWAIT(4));
    // tail: K-tile 17 (buf1)
    PHASE(1, 0, 0, NOSTMT,             NOSTMT);
    PHASE(1, 0, 1, NOSTMT,             VMWAIT(0));
    PHASE(1, 1, 0, NOSTMT,             NOSTMT);
    PHASE(1, 1, 1, NOSTMT,             NOSTMT);

    // ---- epilogue: bias + ReLU. D: col(N)=lane&15, row(M)=fq*4+reg (m89)
#pragma unroll
    for (int j = 0; j < 4; ++j) {
        const int n  = wn * 64 + j * 16 + fr;
        const float bj = bias[n];
#pragma unroll
        for (int i = 0; i < 8; ++i) {
            const int mr = m0 + wm * 128 + i * 16 + fq * 4;
#pragma unroll
            for (int r = 0; r < 4; ++r) {
                const float v = acc[i][j][r] + bj;
                out[(size_t)(mr + r) * COUT + n] = v > 0.f ? v : 0.f;
            }
        }
    }
#undef STAGE_A
#undef STAGE_B
#undef PHASE
}

extern "C" void kernel_launch(void* const* d_in, const int* in_sizes, int n_in,
                              void* d_out, int out_size, void* d_ws, size_t ws_size,
                              hipStream_t stream) {
    const float* in   = (const float*)d_in[0];
    const float* wgt  = (const float*)d_in[1];
    const float* bias = (const float*)d_in[2];
    float* out = (float*)d_out;

    short* pad = (short*)d_ws;
    short* wt  = (short*)d_ws + PAD_ELEMS;

    pack_input<<<PAD_ELEMS / 8 / 256, 256, 0, stream>>>(in, pad);
    pack_wgt<<<dim3(KTOT / 32, COUT / 32), 256, 0, stream>>>(wgt, wt);

    conv_mfma<<<NBLK, 512, 0, stream>>>(pad, wt, bias, out);
}

// Round 2
// 199.124 us; speedup vs baseline: 1.1210x; 1.0296x over previous
//
#include <hip/hip_runtime.h>
#include <hip/hip_bf16.h>

// 3x3 conv pad=1 stride=1, NHWC fp32 -> bf16 MFMA implicit GEMM.
//   M = 32*56*56 = 100352, N = 256, K = 9*128 = 1152
// R6: (a) BM=224 -> grid 448 = 8*56 blocks: dispatch-round efficiency
// 76.6% -> 87.5% (392 blocks over 256 CUs at 1 block/CU wasted round 2).
// (b) phase decomposition (KH,NH) -> (KH,MH): per-phase ds_read profile goes
// from 10/2/10/2 to 8/3/8/3 (m201's shape) -- the 10-read phases put 80
// wave-reads on the LDS pipe fully drained before each MFMA cluster; the
// balanced split levels LDS pipe vs matrix pipe. B-fragments are read in the
// MH0 phase and register-carried into the MH1 phase.  Stage slots, counted
// vmcnt(8) ledger, tail drains identical to R5 (proven / refcheck-passed).
// A-region is 224x32 (14 KB): staging load2 covers rows 128..223 for waves
// 0-5 only; waves 6-7 issue a duplicate of their load1 (same src AND same LDS
// dest -> benign rewrite) so every wave's vmcnt ledger stays uniform -- a
// wave's VMWAIT only guarantees ITS OWN loads, so per-wave load counts must
// match the schedule's assumed ledger.

#define NIMG 32
#define HH 56
#define WW 56
#define PH 58
#define PW 58
#define CIN 128
#define COUT 256
#define KTOT 1152
#define PAD_ELEMS (NIMG * PH * PW * CIN)

#define BM 224
#define BK 64
#define NT (KTOT / BK)                   // 18 K-tiles
#define NBLK ((NIMG * HH * WW) / BM)     // 448 = 8 * 56

// LDS layout (shorts): A regions 224x32 = 7168 shorts (14 KB) x4,
// B regions 256x32 = 8192 shorts (16 KB) x4.  Total 61440 shorts = 120 KiB.
#define AREG_SZ 7168
#define BREG_BASE 28672
#define BREG_SZ 8192

typedef __attribute__((ext_vector_type(8))) short bf16x8;
typedef __attribute__((ext_vector_type(4))) short s16x4;
typedef __attribute__((ext_vector_type(4))) float f32x4;

__device__ __forceinline__ short f2bf(float x) {
    union { __hip_bfloat16 b; short s; } u;
    u.b = __float2bfloat16(x);
    return u.s;
}

typedef const void __attribute__((address_space(1)))* gas1_t;
typedef void __attribute__((address_space(3)))* las3_t;
__device__ __forceinline__ void async16(short* lds_p, const short* g) {
    __builtin_amdgcn_global_load_lds((gas1_t)g, (las3_t)lds_p, 16, 0, 0);
}

// ---- pack 1: fp32 NHWC -> padded bf16 (32,58,58,128), zero halo -------------
__global__ __launch_bounds__(256) void pack_input(const float* __restrict__ in,
                                                  short* __restrict__ pad) {
    const int tid  = blockIdx.x * 256 + threadIdx.x;
    const int flat = tid * 8;
    const int c8   = flat & (CIN - 1);
    const int rest = flat >> 7;
    const int iw   = rest % PW;
    const int r2   = rest / PW;
    const int ih   = r2 % PH;
    const int img  = r2 / PH;
    bf16x8 v = (bf16x8)0;
    if (ih >= 1 && ih <= HH && iw >= 1 && iw <= WW) {
        const float* p = in + (((size_t)(img * HH + ih - 1) * WW + (iw - 1)) * CIN + c8);
        const float4 x0 = *(const float4*)p;
        const float4 x1 = *(const float4*)(p + 4);
        v.s0 = f2bf(x0.x); v.s1 = f2bf(x0.y); v.s2 = f2bf(x0.z); v.s3 = f2bf(x0.w);
        v.s4 = f2bf(x1.x); v.s5 = f2bf(x1.y); v.s6 = f2bf(x1.z); v.s7 = f2bf(x1.w);
    }
    *(bf16x8*)(pad + flat) = v;
}

// ---- pack 2: weights (K=1152, N=256) fp32 -> bf16 transposed [n][k] ---------
__global__ __launch_bounds__(256) void pack_wgt(const float* __restrict__ w,
                                                short* __restrict__ wt) {
    __shared__ short tile[32][33];
    const int k0 = blockIdx.x * 32;
    const int n0 = blockIdx.y * 32;
    const int t  = threadIdx.x;
    {
        const int kl  = t >> 3;
        const int nl4 = (t & 7) * 4;
        const float4 x = *(const float4*)(w + (size_t)(k0 + kl) * COUT + n0 + nl4);
        tile[kl][nl4 + 0] = f2bf(x.x);
        tile[kl][nl4 + 1] = f2bf(x.y);
        tile[kl][nl4 + 2] = f2bf(x.z);
        tile[kl][nl4 + 3] = f2bf(x.w);
    }
    __syncthreads();
    {
        const int nl  = t >> 3;
        const int kl4 = (t & 7) * 4;
        s16x4 v;
        v.x = tile[kl4 + 0][nl];
        v.y = tile[kl4 + 1][nl];
        v.z = tile[kl4 + 2][nl];
        v.w = tile[kl4 + 3][nl];
        *(s16x4*)(wt + (size_t)(n0 + nl) * KTOT + k0 + kl4) = v;
    }
}

// ---- GEMM: 224x256 tile, BK=64, 8-phase schedule, 16x16x32 bf16 MFMA --------
#define FENCE() asm volatile("" ::: "memory")
#define BARRIER() do { FENCE(); __builtin_amdgcn_s_barrier(); FENCE(); } while (0)
#define VMWAIT(N) asm volatile("s_waitcnt vmcnt(" #N ")" ::: "memory")
#define NOSTMT ((void)0)

__global__ __launch_bounds__(512, 2) void conv_mfma(const short* __restrict__ apad,
                                                    const short* __restrict__ bwt,
                                                    const float* __restrict__ bias,
                                                    float* __restrict__ out) {
    __shared__ short lds[61440];   // 120 KiB

    const int t  = threadIdx.x;    // 0..511
    const int l  = t & 63;
    const int w  = t >> 6;         // 0..7
    const int wm = w >> 2;         // 0..1  (M half: 112 rows)
    const int wn = w & 3;          // 0..3  (N quarter: 64 cols)
    const int fr = l & 15;
    const int fq = l >> 4;

    // fragment lane offset (shorts), swizzle folded in (frag row base is a
    // multiple of 16 so (row>>1)&3 == (fr>>1)&3):
    const int laneoff = fr * 32 + ((fq ^ ((fr >> 1) & 3))) * 8;
    const int afb = wm * 3584;     // A frag base: (wm*112)*32 shorts
    const int bfb = wn * 2048;     // B frag base: (wn*64)*32 shorts
    // staging: thread t -> row t>>2, phys chunk t&3; logical kchunk
    // kc = (t&3) ^ ((row>>1)&3) = (t&3) ^ ((t>>3)&3)  (row+128 preserves it)
    const int kcs = (t & 3) ^ ((t >> 3) & 3);

    const int bid = blockIdx.x;
    const int swz = (bid & 7) * (NBLK / 8) + (bid >> 3);   // 448 = 8*56, bijective
    const int m0  = swz * BM;

    // global row bases for staging (rows r0, and r0+128 for waves 0..5)
    const int r0 = t >> 2;         // 0..127
    int abase0, abase1;
    {
        int m = m0 + r0;
        int img = m / (HH * WW), rem = m - img * (HH * WW);
        int oh = rem / WW, ow = rem - oh * WW;
        abase0 = ((img * PH + oh) * PW + ow) * CIN;
        if (t < 384) {             // rows 128..223 (waves 0..5)
            m = m0 + r0 + 128;
            img = m / (HH * WW); rem = m - img * (HH * WW);
            oh = rem / WW; ow = rem - oh * WW;
            abase1 = ((img * PH + oh) * PW + ow) * CIN;
        } else {
            abase1 = abase0;       // waves 6,7: duplicate of load1 (dummy)
        }
    }
    // A-stage load2 LDS offset: real slot for waves 0..5, load1 slot for 6,7
    const int a2lds = (w < 6) ? (4096 + w * 512) : (w * 512);
    const int bbase0 = r0 * KTOT;
    const int bbase1 = (r0 + 128) * KTOT;

    f32x4 acc[7][4];
#pragma unroll
    for (int i = 0; i < 7; ++i)
#pragma unroll
        for (int j = 0; j < 4; ++j) { f32x4 z = {0.f, 0.f, 0.f, 0.f}; acc[i][j] = z; }

    bf16x8 af0[4], af1[3], bf[4];

    // K-tile KT covers tap = KT>>1 (CIN=128, BK=64), channel base (KT&1)*64.
#define STAGE_A(KT, KH) do {                                                  \
        const int _tap = (KT) >> 1;                                           \
        const int _fh  = (_tap * 11) >> 5;   /* /3 for 0..8 */                \
        const int _fw  = _tap - 3 * _fh;                                      \
        const int _off = (_fh * PW + _fw) * CIN + ((KT) & 1) * 64             \
                         + (KH) * 32 + kcs * 8;                               \
        short* _l = lds + ((((KT) & 1) << 1) + (KH)) * AREG_SZ;               \
        async16(_l + w * 512, apad + abase0 + _off);                          \
        async16(_l + a2lds,   apad + abase1 + _off);                          \
    } while (0)

#define STAGE_B(KT, KH) do {                                                  \
        const int _off = (KT) * 64 + (KH) * 32 + kcs * 8;                     \
        short* _l = lds + BREG_BASE + ((((KT) & 1) << 1) + (KH)) * BREG_SZ;   \
        async16(_l + w * 512,        bwt + bbase0 + _off);                    \
        async16(_l + 4096 + w * 512, bwt + bbase1 + _off);                    \
    } while (0)

    // MH0 phase: read af0[0..3] + bf[0..3] (8 ds_read_b128), 16 MFMA (i 0..3)
#define PH_MH0(BUF, KH, STAGE_STMT, WAIT_STMT) do {                           \
        const short* _a = lds + (((BUF) << 1) + (KH)) * AREG_SZ;              \
        const short* _b = lds + BREG_BASE + (((BUF) << 1) + (KH)) * BREG_SZ;  \
        _Pragma("unroll")                                                     \
        for (int _i = 0; _i < 4; ++_i)                                        \
            af0[_i] = *(const bf16x8*)(_a + afb + _i * 512 + laneoff);        \
        _Pragma("unroll")                                                     \
        for (int _j = 0; _j < 4; ++_j)                                        \
            bf[_j] = *(const bf16x8*)(_b + bfb + _j * 512 + laneoff);         \
        STAGE_STMT;                                                           \
        BARRIER();                                                            \
        __builtin_amdgcn_s_setprio(1);                                        \
        _Pragma("unroll")                                                     \
        for (int _i = 0; _i < 4; ++_i)                                        \
            _Pragma("unroll")                                                 \
            for (int _j = 0; _j < 4; ++_j)                                    \
                acc[_i][_j] = __builtin_amdgcn_mfma_f32_16x16x32_bf16(        \
                    af0[_i], bf[_j], acc[_i][_j], 0, 0, 0);                   \
        __builtin_amdgcn_s_setprio(0);                                        \
        WAIT_STMT;                                                            \
        BARRIER();                                                            \
    } while (0)

    // MH1 phase: read af1[0..2] (3 ds_read_b128), 12 MFMA (i 4..6), reuse bf
#define PH_MH1(BUF, KH, STAGE_STMT, WAIT_STMT) do {                           \
        const short* _a = lds + (((BUF) << 1) + (KH)) * AREG_SZ;              \
        _Pragma("unroll")                                                     \
        for (int _i = 0; _i < 3; ++_i)                                        \
            af1[_i] = *(const bf16x8*)(_a + afb + 2048 + _i * 512 + laneoff); \
        STAGE_STMT;                                                           \
        BARRIER();                                                            \
        __builtin_amdgcn_s_setprio(1);                                        \
        _Pragma("unroll")                                                     \
        for (int _i = 0; _i < 3; ++_i)                                        \
            _Pragma("unroll")                                                 \
            for (int _j = 0; _j < 4; ++_j)                                    \
                acc[4 + _i][_j] = __builtin_amdgcn_mfma_f32_16x16x32_bf16(    \
                    af1[_i], bf[_j], acc[4 + _i][_j], 0, 0, 0);               \
        __builtin_amdgcn_s_setprio(0);                                        \
        WAIT_STMT;                                                            \
        BARRIER();                                                            \
    } while (0)

    // prologue: tile 0 fully + tile 1 khalf0 (6 half-stages, 12 loads/wave);
    // VMWAIT(8) completes the oldest 4 loads = A(0,0),B(0,0) = phase-0 reads.
    STAGE_A(0, 0); STAGE_B(0, 0);
    STAGE_A(0, 1); STAGE_B(0, 1);
    STAGE_A(1, 0); STAGE_B(1, 0);
    VMWAIT(8);
    BARRIER();

#pragma unroll 1
    for (int kt = 0; kt < NT - 2; kt += 2) {
        // K-tile kt (buf0)
        PH_MH0(0, 0, STAGE_A(kt + 1, 1), NOSTMT);
        PH_MH1(0, 0, STAGE_B(kt + 1, 1), VMWAIT(8));
        PH_MH0(0, 1, STAGE_A(kt + 2, 0), NOSTMT);
        PH_MH1(0, 1, STAGE_B(kt + 2, 0), VMWAIT(8));
        // K-tile kt+1 (buf1)
        PH_MH0(1, 0, STAGE_A(kt + 2, 1), NOSTMT);
        PH_MH1(1, 0, STAGE_B(kt + 2, 1), VMWAIT(8));
        PH_MH0(1, 1, STAGE_A(kt + 3, 0), NOSTMT);
        PH_MH1(1, 1, STAGE_B(kt + 3, 0), VMWAIT(8));
    }
    // tail: K-tile 16 (buf0) -- last real stages, drain waits
    PH_MH0(0, 0, STAGE_A(NT - 1, 1), NOSTMT);
    PH_MH1(0, 0, STAGE_B(NT - 1, 1), VMWAIT(8));
    PH_MH0(0, 1, NOSTMT,             NOSTMT);
    PH_MH1(0, 1, NOSTMT,             VMWAIT(4));
    // tail: K-tile 17 (buf1)
    PH_MH0(1, 0, NOSTMT,             NOSTMT);
    PH_MH1(1, 0, NOSTMT,             VMWAIT(0));
    PH_MH0(1, 1, NOSTMT,             NOSTMT);
    PH_MH1(1, 1, NOSTMT,             NOSTMT);

    // ---- epilogue: bias + ReLU. D: col(N)=lane&15, row(M)=fq*4+reg (m89)
#pragma unroll
    for (int j = 0; j < 4; ++j) {
        const int n  = wn * 64 + j * 16 + fr;
        const float bj = bias[n];
#pragma unroll
        for (int i = 0; i < 7; ++i) {
            const int mr = m0 + wm * 112 + i * 16 + fq * 4;
#pragma unroll
            for (int r = 0; r < 4; ++r) {
                const float v = acc[i][j][r] + bj;
                out[(size_t)(mr + r) * COUT + n] = v > 0.f ? v : 0.f;
            }
        }
    }
#undef STAGE_A
#undef STAGE_B
#undef PH_MH0
#undef PH_MH1
}

extern "C" void kernel_launch(void* const* d_in, const int* in_sizes, int n_in,
                              void* d_out, int out_size, void* d_ws, size_t ws_size,
                              hipStream_t stream) {
    const float* in   = (const float*)d_in[0];
    const float* wgt  = (const float*)d_in[1];
    const float* bias = (const float*)d_in[2];
    float* out = (float*)d_out;

    short* pad = (short*)d_ws;
    short* wt  = (short*)d_ws + PAD_ELEMS;

    pack_input<<<PAD_ELEMS / 8 / 256, 256, 0, stream>>>(in, pad);
    pack_wgt<<<dim3(KTOT / 32, COUT / 32), 256, 0, stream>>>(wgt, wt);

    conv_mfma<<<NBLK, 512, 0, stream>>>(pad, wt, bias, out);
}